// Round 5
// baseline (530.016 us; speedup 1.0000x reference)
//
#include <hip/hip_runtime.h>

// GCNLinkPredictor: 2-layer GCN, N=100000, E=3.2M, F=128, U=1000.
// R5: GEMM restructure. R4's gemm had a 32-way LDS bank conflict on the Xs
// transpose stores (stride 128 words == 0 mod 32) and 80KB LDS -> 2 blocks/CU.
// Now: no X LDS tile (X read from global as half-wave broadcast float4 -> one
// L1 request), W staged in two 64-row halves (32KB LDS -> 5 blocks/CU).

#define F_DIM 128
#define U_USERS 1000
#define SCAN_CHUNK 1024
#define NFCAP 48000     // frontier cap (expected ~33K)
#define NCHUNK 3        // node-space chunks for histogram
#define SBIN 40960      // nodes per chunk (3*40960 >= 100000)
#define SW (SBIN / 2)   // packed words per chunk (2 x u16 per word)
#define PSLICE 85       // edge slices per chunk -> 255 blocks

// ---- histogram: LDS packed counters, no global atomics ----
__global__ __launch_bounds__(1024) void hist_kernel(const int* __restrict__ src,
                                                    const int* __restrict__ dst,
                                                    unsigned int* __restrict__ partial,
                                                    int* __restrict__ fr, int E, int n) {
    __shared__ unsigned int h[SW];   // 80 KB
    int tid = threadIdx.x;
    int c = blockIdx.x % NCHUNK;
    int p = blockIdx.x / NCHUNK;
    for (int i = tid; i < SW; i += 1024) h[i] = 0u;
    __syncthreads();

    int lo = c * SBIN;
    int hi = lo + SBIN;
    int len = (E + PSLICE - 1) / PSLICE;
    int base = p * len;
    int end = min(E, base + len);
    for (int e = base + tid; e < end; e += 1024) {
        int d = dst[e];
        if ((unsigned)d < (unsigned)n) {
            if (d >= lo && d < hi) {
                int local = d - lo;
                atomicAdd(&h[local >> 1], 1u << ((local & 1) << 4));  // LDS atomic
            }
            if (c == 0 && d < U_USERS) {
                int s = src[e];
                if ((unsigned)s < (unsigned)n) fr[s] = 1;
            }
        }
    }
    __syncthreads();
    unsigned int* outp = partial + ((size_t)(c * PSLICE + p)) * SW;
    for (int i = tid; i < SW; i += 1024) outp[i] = h[i];
}

// ---- reduce partials -> deg; fused prep: inv, degF, fr[i<U]=1 ----
__global__ void reduce_prep_kernel(const unsigned int* __restrict__ partial,
                                   float* __restrict__ inv, int* __restrict__ fr,
                                   int* __restrict__ degF, int n) {
    int t = blockIdx.x * blockDim.x + threadIdx.x;
    if (t >= NCHUNK * SW) return;
    int c = t / SW, w = t % SW;
    unsigned int a0 = 0, a1 = 0;
    const unsigned int* basep = partial + (size_t)c * PSLICE * SW + w;
#pragma unroll 5
    for (int p = 0; p < PSLICE; ++p) {
        unsigned int v = basep[(size_t)p * SW];
        a0 += v & 0xFFFFu;
        a1 += v >> 16;
    }
    int i0 = c * SBIN + 2 * w;
#pragma unroll
    for (int k = 0; k < 2; ++k) {
        int i = i0 + k;
        unsigned int dg = k ? a1 : a0;
        if (i < n) {
            inv[i] = rsqrtf((float)dg + 1.0f);
            bool isfr = (i < U_USERS) || (fr[i] != 0);
            if (i < U_USERS) fr[i] = 1;
            degF[i] = isfr ? (int)dg : 0;
        }
    }
}

// ---- dual exclusive scan (degF -> rp, fr -> remap), 3 kernels ----
__global__ void scan_reduce2_kernel(const int* __restrict__ dA, const int* __restrict__ dB,
                                    int* __restrict__ pA, int* __restrict__ pB, int n) {
    __shared__ int sdata[256];
    int b = blockIdx.x, t = threadIdx.x;
    int base = b * SCAN_CHUNK;
    int sumA = 0, sumB = 0;
#pragma unroll
    for (int i = 0; i < 4; ++i) {
        int idx = base + t + 256 * i;
        if (idx < n) { sumA += dA[idx]; sumB += dB[idx]; }
    }
    sdata[t] = sumA; __syncthreads();
    for (int s = 128; s > 0; s >>= 1) { if (t < s) sdata[t] += sdata[t + s]; __syncthreads(); }
    if (t == 0) pA[b] = sdata[0];
    __syncthreads();
    sdata[t] = sumB; __syncthreads();
    for (int s = 128; s > 0; s >>= 1) { if (t < s) sdata[t] += sdata[t + s]; __syncthreads(); }
    if (t == 0) pB[b] = sdata[0];
}

__global__ void scan_partials2_kernel(int* __restrict__ pA, int* __restrict__ pB, int nb) {
    int t = threadIdx.x;
    if (t == 0)  { int run = 0; for (int i = 0; i < nb; ++i) { int v = pA[i]; pA[i] = run; run += v; } }
    if (t == 64) { int run = 0; for (int i = 0; i < nb; ++i) { int v = pB[i]; pB[i] = run; run += v; } }
}

__global__ void scan_final2_kernel(const int* __restrict__ dA, const int* __restrict__ pA,
                                   int* __restrict__ rp,
                                   const int* __restrict__ dB, const int* __restrict__ pB,
                                   int* __restrict__ remap,
                                   int* __restrict__ flist, int* __restrict__ nf_dev, int n) {
    __shared__ int sthread[256];
    int b = blockIdx.x, t = threadIdx.x;
    int base = b * SCAN_CHUNK;
    {
        int v[4]; int sum = 0;
#pragma unroll
        for (int i = 0; i < 4; ++i) { int idx = base + 4 * t + i; v[i] = (idx < n) ? dA[idx] : 0; sum += v[i]; }
        sthread[t] = sum; __syncthreads();
        for (int ofs = 1; ofs < 256; ofs <<= 1) {
            int val = (t >= ofs) ? sthread[t - ofs] : 0;
            __syncthreads(); sthread[t] += val; __syncthreads();
        }
        int run = sthread[t] - sum + pA[b];
#pragma unroll
        for (int i = 0; i < 4; ++i) { int idx = base + 4 * t + i; if (idx < n) rp[idx] = run; run += v[i]; }
        __syncthreads();
    }
    {
        int v[4]; int sum = 0;
#pragma unroll
        for (int i = 0; i < 4; ++i) { int idx = base + 4 * t + i; v[i] = (idx < n) ? dB[idx] : 0; sum += v[i]; }
        sthread[t] = sum; __syncthreads();
        for (int ofs = 1; ofs < 256; ofs <<= 1) {
            int val = (t >= ofs) ? sthread[t - ofs] : 0;
            __syncthreads(); sthread[t] += val; __syncthreads();
        }
        int run = sthread[t] - sum + pB[b];
#pragma unroll
        for (int i = 0; i < 4; ++i) {
            int idx = base + 4 * t + i;
            if (idx < n) {
                remap[idx] = run;
                if (v[i] && run < NFCAP) flist[run] = idx;
                if (idx == n - 1) *nf_dev = min(run + v[i], NFCAP);
            }
            run += v[i];
        }
    }
}

// ---- CSR fill (frontier rows only) ----
__global__ void fill_csr_kernel(const int* __restrict__ src, const int* __restrict__ dst,
                                const int* __restrict__ fr,
                                int* __restrict__ rp, int* __restrict__ col, int E, int n) {
    int e = blockIdx.x * blockDim.x + threadIdx.x;
    if (e < E) {
        int d = dst[e], s = src[e];
        if ((unsigned)d < (unsigned)n && (unsigned)s < (unsigned)n && fr[d]) {
            int pos = atomicAdd(&rp[d], 1);
            if ((unsigned)pos < (unsigned)E) col[pos] = s;
        }
    }
}

// ---- dense GEMM v2: out[n,128] = X[n,128] @ W[128,128] ----
// 256 threads, 32 rows/block. W staged per 64-row k-half (32KB LDS -> 5
// blocks/CU). X read directly from global: half-wave lanes share the address
// (one L1 request), each element fetched once per grid. No LDS conflicts:
// Ws b128 reads are consecutive-lane-consecutive-float4.
__global__ __launch_bounds__(256) void gemm_nn_kernel(const float* __restrict__ X,
                                                      const float* __restrict__ W,
                                                      float* __restrict__ out, int nrows) {
    __shared__ float Ws[64 * F_DIM];   // 32 KB

    int tid = threadIdx.x;
    int c = tid & 31;              // col group: cols [4c, 4c+4)
    int r0 = (tid >> 5) * 4;       // rows [r0, r0+4) within tile
    int rowBase = blockIdx.x * 32;

    float4 acc[4];
#pragma unroll
    for (int i = 0; i < 4; ++i) acc[i] = make_float4(0.f, 0.f, 0.f, 0.f);

    for (int p = 0; p < 2; ++p) {
        __syncthreads();
        const float4* Wp4 = (const float4*)(W + (size_t)p * 64 * F_DIM);
        float4* Ws4 = (float4*)Ws;
#pragma unroll
        for (int i = 0; i < 8; ++i) Ws4[tid + 256 * i] = Wp4[tid + 256 * i];
        __syncthreads();

        const float* Xp = X + p * 64;     // k offset into X row
#pragma unroll 4
        for (int kg = 0; kg < 16; ++kg) {
            int k0 = kg * 4;
            float4 xv[4];
#pragma unroll
            for (int i = 0; i < 4; ++i) {
                int row = rowBase + r0 + i;
                xv[i] = (row < nrows)
                          ? *(const float4*)(Xp + (size_t)row * F_DIM + k0)
                          : make_float4(0.f, 0.f, 0.f, 0.f);
            }
#pragma unroll
            for (int kk = 0; kk < 4; ++kk) {
                float4 wv = *(const float4*)(Ws + (k0 + kk) * F_DIM + 4 * c);
                float xs0 = ((const float*)&xv[0])[kk];
                float xs1 = ((const float*)&xv[1])[kk];
                float xs2 = ((const float*)&xv[2])[kk];
                float xs3 = ((const float*)&xv[3])[kk];
                acc[0].x += xs0 * wv.x; acc[0].y += xs0 * wv.y; acc[0].z += xs0 * wv.z; acc[0].w += xs0 * wv.w;
                acc[1].x += xs1 * wv.x; acc[1].y += xs1 * wv.y; acc[1].z += xs1 * wv.z; acc[1].w += xs1 * wv.w;
                acc[2].x += xs2 * wv.x; acc[2].y += xs2 * wv.y; acc[2].z += xs2 * wv.z; acc[2].w += xs2 * wv.w;
                acc[3].x += xs3 * wv.x; acc[3].y += xs3 * wv.y; acc[3].z += xs3 * wv.z; acc[3].w += xs3 * wv.w;
            }
        }
    }

#pragma unroll
    for (int i = 0; i < 4; ++i) {
        int row = rowBase + r0 + i;
        if (row < nrows)
            ((float4*)(out + (size_t)row * F_DIM))[c] = acc[i];
    }
}

// ---- GEMM v2 with device-side row count ----
__global__ __launch_bounds__(256) void gemm_nn_dyn_kernel(const float* __restrict__ X,
                                                          const float* __restrict__ W,
                                                          float* __restrict__ out,
                                                          const int* __restrict__ nrows_p) {
    int nrows = *nrows_p;
    int rowBase = blockIdx.x * 32;
    if (rowBase >= nrows) return;

    __shared__ float Ws[64 * F_DIM];

    int tid = threadIdx.x;
    int c = tid & 31;
    int r0 = (tid >> 5) * 4;

    float4 acc[4];
#pragma unroll
    for (int i = 0; i < 4; ++i) acc[i] = make_float4(0.f, 0.f, 0.f, 0.f);

    for (int p = 0; p < 2; ++p) {
        __syncthreads();
        const float4* Wp4 = (const float4*)(W + (size_t)p * 64 * F_DIM);
        float4* Ws4 = (float4*)Ws;
#pragma unroll
        for (int i = 0; i < 8; ++i) Ws4[tid + 256 * i] = Wp4[tid + 256 * i];
        __syncthreads();

        const float* Xp = X + p * 64;
#pragma unroll 4
        for (int kg = 0; kg < 16; ++kg) {
            int k0 = kg * 4;
            float4 xv[4];
#pragma unroll
            for (int i = 0; i < 4; ++i) {
                int row = rowBase + r0 + i;
                xv[i] = (row < nrows)
                          ? *(const float4*)(Xp + (size_t)row * F_DIM + k0)
                          : make_float4(0.f, 0.f, 0.f, 0.f);
            }
#pragma unroll
            for (int kk = 0; kk < 4; ++kk) {
                float4 wv = *(const float4*)(Ws + (k0 + kk) * F_DIM + 4 * c);
                float xs0 = ((const float*)&xv[0])[kk];
                float xs1 = ((const float*)&xv[1])[kk];
                float xs2 = ((const float*)&xv[2])[kk];
                float xs3 = ((const float*)&xv[3])[kk];
                acc[0].x += xs0 * wv.x; acc[0].y += xs0 * wv.y; acc[0].z += xs0 * wv.z; acc[0].w += xs0 * wv.w;
                acc[1].x += xs1 * wv.x; acc[1].y += xs1 * wv.y; acc[1].z += xs1 * wv.z; acc[1].w += xs1 * wv.w;
                acc[2].x += xs2 * wv.x; acc[2].y += xs2 * wv.y; acc[2].z += xs2 * wv.z; acc[2].w += xs2 * wv.w;
                acc[3].x += xs3 * wv.x; acc[3].y += xs3 * wv.y; acc[3].z += xs3 * wv.z; acc[3].w += xs3 * wv.w;
            }
        }
    }

#pragma unroll
    for (int i = 0; i < 4; ++i) {
        int row = rowBase + r0 + i;
        if (row < nrows)
            ((float4*)(out + (size_t)row * F_DIM))[c] = acc[i];
    }
}

// ---- layer-1 gather over compact frontier rows ----
__global__ __launch_bounds__(256) void gather_l1_kernel(const float* __restrict__ xw,
                                                        const float* __restrict__ inv,
                                                        const int* __restrict__ rp,
                                                        const int* __restrict__ col,
                                                        const int* __restrict__ flist,
                                                        const int* __restrict__ nf_p,
                                                        const float* __restrict__ b,
                                                        float* __restrict__ h1c) {
    int ci = blockIdx.x * 4 + (threadIdx.x >> 6);
    if (ci >= *nf_p) return;
    int lane = threadIdx.x & 63;
    int node = flist[ci];
    int start = (node == 0) ? 0 : rp[node - 1];
    int end = rp[node];

    float accx = 0.f, accy = 0.f;
    for (int base = start; base < end; base += 64) {
        int j = base + lane;
        int s_l = 0; float c_l = 0.f;
        if (j < end) { s_l = col[j]; c_l = inv[s_l]; }
        int cnt = min(64, end - base);
        int i = 0;
        for (; i + 4 <= cnt; i += 4) {
            int s0 = __shfl(s_l, i + 0); float f0 = __shfl(c_l, i + 0);
            int s1 = __shfl(s_l, i + 1); float f1 = __shfl(c_l, i + 1);
            int s2 = __shfl(s_l, i + 2); float f2 = __shfl(c_l, i + 2);
            int s3 = __shfl(s_l, i + 3); float f3 = __shfl(c_l, i + 3);
            float2 v0 = ((const float2*)(xw + (size_t)s0 * F_DIM))[lane];
            float2 v1 = ((const float2*)(xw + (size_t)s1 * F_DIM))[lane];
            float2 v2 = ((const float2*)(xw + (size_t)s2 * F_DIM))[lane];
            float2 v3 = ((const float2*)(xw + (size_t)s3 * F_DIM))[lane];
            accx += v0.x * f0 + v1.x * f1 + v2.x * f2 + v3.x * f3;
            accy += v0.y * f0 + v1.y * f1 + v2.y * f2 + v3.y * f3;
        }
        for (; i < cnt; ++i) {
            int s0 = __shfl(s_l, i); float f0 = __shfl(c_l, i);
            float2 v0 = ((const float2*)(xw + (size_t)s0 * F_DIM))[lane];
            accx += v0.x * f0;
            accy += v0.y * f0;
        }
    }

    float ivd = inv[node];
    float2 self = ((const float2*)(xw + (size_t)node * F_DIM))[lane];
    float vx = accx * ivd + self.x * ivd * ivd + b[lane * 2];
    float vy = accy * ivd + self.y * ivd * ivd + b[lane * 2 + 1];
    vx = vx > 0.f ? vx : expf(vx) - 1.f;
    vy = vy > 0.f ? vy : expf(vy) - 1.f;
    ((float2*)(h1c + (size_t)ci * F_DIM))[lane] = make_float2(vx, vy);
}

// ---- layer-2 gather over rows [0,U) ----
__global__ __launch_bounds__(256) void gather_l2_kernel(const float* __restrict__ xwc,
                                                        const float* __restrict__ inv,
                                                        const int* __restrict__ rp,
                                                        const int* __restrict__ col,
                                                        const int* __restrict__ remap,
                                                        const float* __restrict__ b,
                                                        float* __restrict__ out) {
    int node = blockIdx.x * 4 + (threadIdx.x >> 6);
    if (node >= U_USERS) return;
    int lane = threadIdx.x & 63;
    int start = (node == 0) ? 0 : rp[node - 1];
    int end = rp[node];

    float accx = 0.f, accy = 0.f;
    for (int base = start; base < end; base += 64) {
        int j = base + lane;
        int r_l = 0; float c_l = 0.f;
        if (j < end) { int s = col[j]; c_l = inv[s]; r_l = remap[s]; }
        int cnt = min(64, end - base);
        for (int i = 0; i < cnt; ++i) {
            int rr = __shfl(r_l, i); float f0 = __shfl(c_l, i);
            float2 v0 = ((const float2*)(xwc + (size_t)rr * F_DIM))[lane];
            accx += v0.x * f0;
            accy += v0.y * f0;
        }
    }

    float ivd = inv[node];
    float2 self = ((const float2*)(xwc + (size_t)node * F_DIM))[lane];
    float vx = accx * ivd + self.x * ivd * ivd + b[lane * 2];
    float vy = accy * ivd + self.y * ivd * ivd + b[lane * 2 + 1];
    vx = vx > 0.f ? vx : expf(vx) - 1.f;
    vy = vy > 0.f ? vy : expf(vy) - 1.f;
    ((float2*)(out + (size_t)node * F_DIM))[lane] = make_float2(vx, vy);
}

extern "C" void kernel_launch(void* const* d_in, const int* in_sizes, int n_in,
                              void* d_out, int out_size, void* d_ws, size_t ws_size,
                              hipStream_t stream) {
    const float* x  = (const float*)d_in[0];
    const int*   ei = (const int*)d_in[1];   // [2, E] int32
    const float* W1 = (const float*)d_in[2];
    const float* b1 = (const float*)d_in[3];
    const float* W2 = (const float*)d_in[4];
    const float* b2 = (const float*)d_in[5];
    float* out = (float*)d_out;

    int n = in_sizes[0] / F_DIM;   // 100000
    int E = in_sizes[1] / 2;       // 3200000
    const int* srcI = ei;
    const int* dstI = ei + E;

    // workspace layout (~112 MB)
    float* xw    = (float*)d_ws;                     // n*128 f (xw1; reused as xwc)
    float* h1c   = xw + (size_t)n * F_DIM;           // NFCAP*128 f
    float* inv   = h1c + (size_t)NFCAP * F_DIM;      // n f
    int* fr      = (int*)(inv + n);                  // n
    int* degF    = fr + n;                           // n
    int* remap   = degF + n;                         // n
    int* rp      = remap + n;                        // n
    int* flist   = rp + n;                           // NFCAP
    int* pA      = flist + NFCAP;                    // 1024
    int* pB      = pA + 1024;                        // 1024
    int* nf_dev  = pB + 1024;                        // 1 (+pad)
    int* col     = nf_dev + 16;                      // E
    unsigned int* partialH = (unsigned int*)(col + E);  // NCHUNK*PSLICE*SW

    int nb = (n + SCAN_CHUNK - 1) / SCAN_CHUNK;      // 98

    hipMemsetAsync(fr, 0, (size_t)n * sizeof(int), stream);

    hist_kernel<<<NCHUNK * PSLICE, 1024, 0, stream>>>(srcI, dstI, partialH, fr, E, n);
    reduce_prep_kernel<<<(NCHUNK * SW + 255) / 256, 256, 0, stream>>>(partialH, inv, fr, degF, n);

    scan_reduce2_kernel<<<nb, 256, 0, stream>>>(degF, fr, pA, pB, n);
    scan_partials2_kernel<<<1, 128, 0, stream>>>(pA, pB, nb);
    scan_final2_kernel<<<nb, 256, 0, stream>>>(degF, pA, rp, fr, pB, remap, flist, nf_dev, n);

    fill_csr_kernel<<<(E + 255) / 256, 256, 0, stream>>>(srcI, dstI, fr, rp, col, E, n);

    // layer 1: full GEMM, frontier-only gather
    gemm_nn_kernel<<<(n + 31) / 32, 256, 0, stream>>>(x, W1, xw, n);
    gather_l1_kernel<<<(NFCAP + 3) / 4, 256, 0, stream>>>(xw, inv, rp, col, flist, nf_dev, b1, h1c);

    // layer 2: compact GEMM (nf rows), gather over U rows
    gemm_nn_dyn_kernel<<<(NFCAP + 31) / 32, 256, 0, stream>>>(h1c, W2, xw, nf_dev);
    gather_l2_kernel<<<(U_USERS + 3) / 4, 256, 0, stream>>>(xw, inv, rp, col, remap, b2, out);

    // passthrough rows [U:]
    hipMemcpyAsync(out + (size_t)U_USERS * F_DIM, x + (size_t)U_USERS * F_DIM,
                   (size_t)(n - U_USERS) * F_DIM * sizeof(float),
                   hipMemcpyDeviceToDevice, stream);
}

// Round 6
// 395.990 us; speedup vs baseline: 1.3385x; 1.3385x over previous
//
#include <hip/hip_runtime.h>

// GCNLinkPredictor: 2-layer GCN, N=100000, E=3.2M, F=128, U=1000.
// R6: GEMM v3. R4 = X-in-LDS but transposed stores -> 32-way bank conflicts
// (1.24e7 cyc); R5 = X-from-global -> vmcnt-latency-bound (VALUBusy 21%).
// v3 keeps X in LDS row-major: staging stores are consecutive-float4 (min
// aliasing), inner reads are half-wave broadcasts (free) + conflict-free W
// b128. W staged per 64-row k-half: 48KB LDS -> 3 blocks/CU (37.5% occ).

#define F_DIM 128
#define U_USERS 1000
#define SCAN_CHUNK 1024
#define NFCAP 48000     // frontier cap (expected ~33K)
#define NCHUNK 3        // node-space chunks for histogram
#define SBIN 40960      // nodes per chunk (3*40960 >= 100000)
#define SW (SBIN / 2)   // packed words per chunk (2 x u16 per word)
#define PSLICE 85       // edge slices per chunk -> 255 blocks

// ---- histogram: LDS packed counters, no global atomics ----
__global__ __launch_bounds__(1024) void hist_kernel(const int* __restrict__ src,
                                                    const int* __restrict__ dst,
                                                    unsigned int* __restrict__ partial,
                                                    int* __restrict__ fr, int E, int n) {
    __shared__ unsigned int h[SW];   // 80 KB
    int tid = threadIdx.x;
    int c = blockIdx.x % NCHUNK;
    int p = blockIdx.x / NCHUNK;
    for (int i = tid; i < SW; i += 1024) h[i] = 0u;
    __syncthreads();

    int lo = c * SBIN;
    int hi = lo + SBIN;
    int len = (E + PSLICE - 1) / PSLICE;
    int base = p * len;
    int end = min(E, base + len);
    for (int e = base + tid; e < end; e += 1024) {
        int d = dst[e];
        if ((unsigned)d < (unsigned)n) {
            if (d >= lo && d < hi) {
                int local = d - lo;
                atomicAdd(&h[local >> 1], 1u << ((local & 1) << 4));  // LDS atomic
            }
            if (c == 0 && d < U_USERS) {
                int s = src[e];
                if ((unsigned)s < (unsigned)n) fr[s] = 1;
            }
        }
    }
    __syncthreads();
    unsigned int* outp = partial + ((size_t)(c * PSLICE + p)) * SW;
    for (int i = tid; i < SW; i += 1024) outp[i] = h[i];
}

// ---- reduce partials -> deg; fused prep: inv, degF, fr[i<U]=1 ----
__global__ void reduce_prep_kernel(const unsigned int* __restrict__ partial,
                                   float* __restrict__ inv, int* __restrict__ fr,
                                   int* __restrict__ degF, int n) {
    int t = blockIdx.x * blockDim.x + threadIdx.x;
    if (t >= NCHUNK * SW) return;
    int c = t / SW, w = t % SW;
    unsigned int a0 = 0, a1 = 0;
    const unsigned int* basep = partial + (size_t)c * PSLICE * SW + w;
#pragma unroll 5
    for (int p = 0; p < PSLICE; ++p) {
        unsigned int v = basep[(size_t)p * SW];
        a0 += v & 0xFFFFu;
        a1 += v >> 16;
    }
    int i0 = c * SBIN + 2 * w;
#pragma unroll
    for (int k = 0; k < 2; ++k) {
        int i = i0 + k;
        unsigned int dg = k ? a1 : a0;
        if (i < n) {
            inv[i] = rsqrtf((float)dg + 1.0f);
            bool isfr = (i < U_USERS) || (fr[i] != 0);
            if (i < U_USERS) fr[i] = 1;
            degF[i] = isfr ? (int)dg : 0;
        }
    }
}

// ---- dual exclusive scan (degF -> rp, fr -> remap), 3 kernels ----
__global__ void scan_reduce2_kernel(const int* __restrict__ dA, const int* __restrict__ dB,
                                    int* __restrict__ pA, int* __restrict__ pB, int n) {
    __shared__ int sdata[256];
    int b = blockIdx.x, t = threadIdx.x;
    int base = b * SCAN_CHUNK;
    int sumA = 0, sumB = 0;
#pragma unroll
    for (int i = 0; i < 4; ++i) {
        int idx = base + t + 256 * i;
        if (idx < n) { sumA += dA[idx]; sumB += dB[idx]; }
    }
    sdata[t] = sumA; __syncthreads();
    for (int s = 128; s > 0; s >>= 1) { if (t < s) sdata[t] += sdata[t + s]; __syncthreads(); }
    if (t == 0) pA[b] = sdata[0];
    __syncthreads();
    sdata[t] = sumB; __syncthreads();
    for (int s = 128; s > 0; s >>= 1) { if (t < s) sdata[t] += sdata[t + s]; __syncthreads(); }
    if (t == 0) pB[b] = sdata[0];
}

__global__ void scan_partials2_kernel(int* __restrict__ pA, int* __restrict__ pB, int nb) {
    int t = threadIdx.x;
    if (t == 0)  { int run = 0; for (int i = 0; i < nb; ++i) { int v = pA[i]; pA[i] = run; run += v; } }
    if (t == 64) { int run = 0; for (int i = 0; i < nb; ++i) { int v = pB[i]; pB[i] = run; run += v; } }
}

__global__ void scan_final2_kernel(const int* __restrict__ dA, const int* __restrict__ pA,
                                   int* __restrict__ rp,
                                   const int* __restrict__ dB, const int* __restrict__ pB,
                                   int* __restrict__ remap,
                                   int* __restrict__ flist, int* __restrict__ nf_dev, int n) {
    __shared__ int sthread[256];
    int b = blockIdx.x, t = threadIdx.x;
    int base = b * SCAN_CHUNK;
    {
        int v[4]; int sum = 0;
#pragma unroll
        for (int i = 0; i < 4; ++i) { int idx = base + 4 * t + i; v[i] = (idx < n) ? dA[idx] : 0; sum += v[i]; }
        sthread[t] = sum; __syncthreads();
        for (int ofs = 1; ofs < 256; ofs <<= 1) {
            int val = (t >= ofs) ? sthread[t - ofs] : 0;
            __syncthreads(); sthread[t] += val; __syncthreads();
        }
        int run = sthread[t] - sum + pA[b];
#pragma unroll
        for (int i = 0; i < 4; ++i) { int idx = base + 4 * t + i; if (idx < n) rp[idx] = run; run += v[i]; }
        __syncthreads();
    }
    {
        int v[4]; int sum = 0;
#pragma unroll
        for (int i = 0; i < 4; ++i) { int idx = base + 4 * t + i; v[i] = (idx < n) ? dB[idx] : 0; sum += v[i]; }
        sthread[t] = sum; __syncthreads();
        for (int ofs = 1; ofs < 256; ofs <<= 1) {
            int val = (t >= ofs) ? sthread[t - ofs] : 0;
            __syncthreads(); sthread[t] += val; __syncthreads();
        }
        int run = sthread[t] - sum + pB[b];
#pragma unroll
        for (int i = 0; i < 4; ++i) {
            int idx = base + 4 * t + i;
            if (idx < n) {
                remap[idx] = run;
                if (v[i] && run < NFCAP) flist[run] = idx;
                if (idx == n - 1) *nf_dev = min(run + v[i], NFCAP);
            }
            run += v[i];
        }
    }
}

// ---- CSR fill (frontier rows only) ----
__global__ void fill_csr_kernel(const int* __restrict__ src, const int* __restrict__ dst,
                                const int* __restrict__ fr,
                                int* __restrict__ rp, int* __restrict__ col, int E, int n) {
    int e = blockIdx.x * blockDim.x + threadIdx.x;
    if (e < E) {
        int d = dst[e], s = src[e];
        if ((unsigned)d < (unsigned)n && (unsigned)s < (unsigned)n && fr[d]) {
            int pos = atomicAdd(&rp[d], 1);
            if ((unsigned)pos < (unsigned)E) col[pos] = s;
        }
    }
}

// ---- dense GEMM v3: out[n,128] = X[n,128] @ W[128,128] ----
// 256 threads, 32 rows/block. X tile in LDS row-major (16KB): staging stores
// are lane-consecutive float4 (min aliasing); inner X reads are half-wave
// broadcasts (free). W staged per 64-row k-half (32KB). 48KB total -> 3
// blocks/CU. Inner loop: pure ds_read_b128 + FMA, no global latency.
__global__ __launch_bounds__(256) void gemm_nn_kernel(const float* __restrict__ X,
                                                      const float* __restrict__ W,
                                                      float* __restrict__ out, int nrows) {
    __shared__ float Ws[64 * F_DIM];    // 32 KB
    __shared__ float Xs[32 * F_DIM];    // 16 KB, row-major [r][k]

    int tid = threadIdx.x;
    int c = tid & 31;              // col group: cols [4c, 4c+4)
    int r0 = (tid >> 5) * 4;       // rows [r0, r0+4) within tile
    int rowBase = blockIdx.x * 32;

    // stage X tile row-major: 1024 float4s / 256 threads = 4 each
    float4* Xs4 = (float4*)Xs;
#pragma unroll
    for (int i = 0; i < 4; ++i) {
        int j = tid + 256 * i;      // j = r*32 + k4
        int r = j >> 5;
        int k4 = j & 31;
        int row = rowBase + r;
        float4 v = make_float4(0.f, 0.f, 0.f, 0.f);
        if (row < nrows) v = ((const float4*)(X + (size_t)row * F_DIM))[k4];
        Xs4[j] = v;
    }

    float4 acc[4];
#pragma unroll
    for (int i = 0; i < 4; ++i) acc[i] = make_float4(0.f, 0.f, 0.f, 0.f);

    for (int p = 0; p < 2; ++p) {
        __syncthreads();
        const float4* Wp4 = (const float4*)(W + (size_t)p * 64 * F_DIM);
        float4* Ws4 = (float4*)Ws;
#pragma unroll
        for (int i = 0; i < 8; ++i) Ws4[tid + 256 * i] = Wp4[tid + 256 * i];
        __syncthreads();

#pragma unroll 4
        for (int kg = 0; kg < 16; ++kg) {
            int k0 = kg * 4;                     // local k in [0,64)
            float4 xv[4];
#pragma unroll
            for (int i = 0; i < 4; ++i)
                xv[i] = *(const float4*)(Xs + (r0 + i) * F_DIM + p * 64 + k0);
#pragma unroll
            for (int kk = 0; kk < 4; ++kk) {
                float4 wv = *(const float4*)(Ws + (k0 + kk) * F_DIM + 4 * c);
                float xs0 = ((const float*)&xv[0])[kk];
                float xs1 = ((const float*)&xv[1])[kk];
                float xs2 = ((const float*)&xv[2])[kk];
                float xs3 = ((const float*)&xv[3])[kk];
                acc[0].x += xs0 * wv.x; acc[0].y += xs0 * wv.y; acc[0].z += xs0 * wv.z; acc[0].w += xs0 * wv.w;
                acc[1].x += xs1 * wv.x; acc[1].y += xs1 * wv.y; acc[1].z += xs1 * wv.z; acc[1].w += xs1 * wv.w;
                acc[2].x += xs2 * wv.x; acc[2].y += xs2 * wv.y; acc[2].z += xs2 * wv.z; acc[2].w += xs2 * wv.w;
                acc[3].x += xs3 * wv.x; acc[3].y += xs3 * wv.y; acc[3].z += xs3 * wv.z; acc[3].w += xs3 * wv.w;
            }
        }
    }

#pragma unroll
    for (int i = 0; i < 4; ++i) {
        int row = rowBase + r0 + i;
        if (row < nrows)
            ((float4*)(out + (size_t)row * F_DIM))[c] = acc[i];
    }
}

// ---- GEMM v3 with device-side row count ----
__global__ __launch_bounds__(256) void gemm_nn_dyn_kernel(const float* __restrict__ X,
                                                          const float* __restrict__ W,
                                                          float* __restrict__ out,
                                                          const int* __restrict__ nrows_p) {
    int nrows = *nrows_p;
    int rowBase = blockIdx.x * 32;
    if (rowBase >= nrows) return;

    __shared__ float Ws[64 * F_DIM];
    __shared__ float Xs[32 * F_DIM];

    int tid = threadIdx.x;
    int c = tid & 31;
    int r0 = (tid >> 5) * 4;

    float4* Xs4 = (float4*)Xs;
#pragma unroll
    for (int i = 0; i < 4; ++i) {
        int j = tid + 256 * i;
        int r = j >> 5;
        int k4 = j & 31;
        int row = rowBase + r;
        float4 v = make_float4(0.f, 0.f, 0.f, 0.f);
        if (row < nrows) v = ((const float4*)(X + (size_t)row * F_DIM))[k4];
        Xs4[j] = v;
    }

    float4 acc[4];
#pragma unroll
    for (int i = 0; i < 4; ++i) acc[i] = make_float4(0.f, 0.f, 0.f, 0.f);

    for (int p = 0; p < 2; ++p) {
        __syncthreads();
        const float4* Wp4 = (const float4*)(W + (size_t)p * 64 * F_DIM);
        float4* Ws4 = (float4*)Ws;
#pragma unroll
        for (int i = 0; i < 8; ++i) Ws4[tid + 256 * i] = Wp4[tid + 256 * i];
        __syncthreads();

#pragma unroll 4
        for (int kg = 0; kg < 16; ++kg) {
            int k0 = kg * 4;
            float4 xv[4];
#pragma unroll
            for (int i = 0; i < 4; ++i)
                xv[i] = *(const float4*)(Xs + (r0 + i) * F_DIM + p * 64 + k0);
#pragma unroll
            for (int kk = 0; kk < 4; ++kk) {
                float4 wv = *(const float4*)(Ws + (k0 + kk) * F_DIM + 4 * c);
                float xs0 = ((const float*)&xv[0])[kk];
                float xs1 = ((const float*)&xv[1])[kk];
                float xs2 = ((const float*)&xv[2])[kk];
                float xs3 = ((const float*)&xv[3])[kk];
                acc[0].x += xs0 * wv.x; acc[0].y += xs0 * wv.y; acc[0].z += xs0 * wv.z; acc[0].w += xs0 * wv.w;
                acc[1].x += xs1 * wv.x; acc[1].y += xs1 * wv.y; acc[1].z += xs1 * wv.z; acc[1].w += xs1 * wv.w;
                acc[2].x += xs2 * wv.x; acc[2].y += xs2 * wv.y; acc[2].z += xs2 * wv.z; acc[2].w += xs2 * wv.w;
                acc[3].x += xs3 * wv.x; acc[3].y += xs3 * wv.y; acc[3].z += xs3 * wv.z; acc[3].w += xs3 * wv.w;
            }
        }
    }

#pragma unroll
    for (int i = 0; i < 4; ++i) {
        int row = rowBase + r0 + i;
        if (row < nrows)
            ((float4*)(out + (size_t)row * F_DIM))[c] = acc[i];
    }
}

// ---- layer-1 gather over compact frontier rows ----
__global__ __launch_bounds__(256) void gather_l1_kernel(const float* __restrict__ xw,
                                                        const float* __restrict__ inv,
                                                        const int* __restrict__ rp,
                                                        const int* __restrict__ col,
                                                        const int* __restrict__ flist,
                                                        const int* __restrict__ nf_p,
                                                        const float* __restrict__ b,
                                                        float* __restrict__ h1c) {
    int ci = blockIdx.x * 4 + (threadIdx.x >> 6);
    if (ci >= *nf_p) return;
    int lane = threadIdx.x & 63;
    int node = flist[ci];
    int start = (node == 0) ? 0 : rp[node - 1];
    int end = rp[node];

    float accx = 0.f, accy = 0.f;
    for (int base = start; base < end; base += 64) {
        int j = base + lane;
        int s_l = 0; float c_l = 0.f;
        if (j < end) { s_l = col[j]; c_l = inv[s_l]; }
        int cnt = min(64, end - base);
        int i = 0;
        for (; i + 4 <= cnt; i += 4) {
            int s0 = __shfl(s_l, i + 0); float f0 = __shfl(c_l, i + 0);
            int s1 = __shfl(s_l, i + 1); float f1 = __shfl(c_l, i + 1);
            int s2 = __shfl(s_l, i + 2); float f2 = __shfl(c_l, i + 2);
            int s3 = __shfl(s_l, i + 3); float f3 = __shfl(c_l, i + 3);
            float2 v0 = ((const float2*)(xw + (size_t)s0 * F_DIM))[lane];
            float2 v1 = ((const float2*)(xw + (size_t)s1 * F_DIM))[lane];
            float2 v2 = ((const float2*)(xw + (size_t)s2 * F_DIM))[lane];
            float2 v3 = ((const float2*)(xw + (size_t)s3 * F_DIM))[lane];
            accx += v0.x * f0 + v1.x * f1 + v2.x * f2 + v3.x * f3;
            accy += v0.y * f0 + v1.y * f1 + v2.y * f2 + v3.y * f3;
        }
        for (; i < cnt; ++i) {
            int s0 = __shfl(s_l, i); float f0 = __shfl(c_l, i);
            float2 v0 = ((const float2*)(xw + (size_t)s0 * F_DIM))[lane];
            accx += v0.x * f0;
            accy += v0.y * f0;
        }
    }

    float ivd = inv[node];
    float2 self = ((const float2*)(xw + (size_t)node * F_DIM))[lane];
    float vx = accx * ivd + self.x * ivd * ivd + b[lane * 2];
    float vy = accy * ivd + self.y * ivd * ivd + b[lane * 2 + 1];
    vx = vx > 0.f ? vx : expf(vx) - 1.f;
    vy = vy > 0.f ? vy : expf(vy) - 1.f;
    ((float2*)(h1c + (size_t)ci * F_DIM))[lane] = make_float2(vx, vy);
}

// ---- layer-2 gather over rows [0,U) ----
__global__ __launch_bounds__(256) void gather_l2_kernel(const float* __restrict__ xwc,
                                                        const float* __restrict__ inv,
                                                        const int* __restrict__ rp,
                                                        const int* __restrict__ col,
                                                        const int* __restrict__ remap,
                                                        const float* __restrict__ b,
                                                        float* __restrict__ out) {
    int node = blockIdx.x * 4 + (threadIdx.x >> 6);
    if (node >= U_USERS) return;
    int lane = threadIdx.x & 63;
    int start = (node == 0) ? 0 : rp[node - 1];
    int end = rp[node];

    float accx = 0.f, accy = 0.f;
    for (int base = start; base < end; base += 64) {
        int j = base + lane;
        int r_l = 0; float c_l = 0.f;
        if (j < end) { int s = col[j]; c_l = inv[s]; r_l = remap[s]; }
        int cnt = min(64, end - base);
        for (int i = 0; i < cnt; ++i) {
            int rr = __shfl(r_l, i); float f0 = __shfl(c_l, i);
            float2 v0 = ((const float2*)(xwc + (size_t)rr * F_DIM))[lane];
            accx += v0.x * f0;
            accy += v0.y * f0;
        }
    }

    float ivd = inv[node];
    float2 self = ((const float2*)(xwc + (size_t)node * F_DIM))[lane];
    float vx = accx * ivd + self.x * ivd * ivd + b[lane * 2];
    float vy = accy * ivd + self.y * ivd * ivd + b[lane * 2 + 1];
    vx = vx > 0.f ? vx : expf(vx) - 1.f;
    vy = vy > 0.f ? vy : expf(vy) - 1.f;
    ((float2*)(out + (size_t)node * F_DIM))[lane] = make_float2(vx, vy);
}

extern "C" void kernel_launch(void* const* d_in, const int* in_sizes, int n_in,
                              void* d_out, int out_size, void* d_ws, size_t ws_size,
                              hipStream_t stream) {
    const float* x  = (const float*)d_in[0];
    const int*   ei = (const int*)d_in[1];   // [2, E] int32
    const float* W1 = (const float*)d_in[2];
    const float* b1 = (const float*)d_in[3];
    const float* W2 = (const float*)d_in[4];
    const float* b2 = (const float*)d_in[5];
    float* out = (float*)d_out;

    int n = in_sizes[0] / F_DIM;   // 100000
    int E = in_sizes[1] / 2;       // 3200000
    const int* srcI = ei;
    const int* dstI = ei + E;

    // workspace layout (~112 MB)
    float* xw    = (float*)d_ws;                     // n*128 f (xw1; reused as xwc)
    float* h1c   = xw + (size_t)n * F_DIM;           // NFCAP*128 f
    float* inv   = h1c + (size_t)NFCAP * F_DIM;      // n f
    int* fr      = (int*)(inv + n);                  // n
    int* degF    = fr + n;                           // n
    int* remap   = degF + n;                         // n
    int* rp      = remap + n;                        // n
    int* flist   = rp + n;                           // NFCAP
    int* pA      = flist + NFCAP;                    // 1024
    int* pB      = pA + 1024;                        // 1024
    int* nf_dev  = pB + 1024;                        // 1 (+pad)
    int* col     = nf_dev + 16;                      // E
    unsigned int* partialH = (unsigned int*)(col + E);  // NCHUNK*PSLICE*SW

    int nb = (n + SCAN_CHUNK - 1) / SCAN_CHUNK;      // 98

    hipMemsetAsync(fr, 0, (size_t)n * sizeof(int), stream);

    hist_kernel<<<NCHUNK * PSLICE, 1024, 0, stream>>>(srcI, dstI, partialH, fr, E, n);
    reduce_prep_kernel<<<(NCHUNK * SW + 255) / 256, 256, 0, stream>>>(partialH, inv, fr, degF, n);

    scan_reduce2_kernel<<<nb, 256, 0, stream>>>(degF, fr, pA, pB, n);
    scan_partials2_kernel<<<1, 128, 0, stream>>>(pA, pB, nb);
    scan_final2_kernel<<<nb, 256, 0, stream>>>(degF, pA, rp, fr, pB, remap, flist, nf_dev, n);

    fill_csr_kernel<<<(E + 255) / 256, 256, 0, stream>>>(srcI, dstI, fr, rp, col, E, n);

    // layer 1: full GEMM, frontier-only gather
    gemm_nn_kernel<<<(n + 31) / 32, 256, 0, stream>>>(x, W1, xw, n);
    gather_l1_kernel<<<(NFCAP + 3) / 4, 256, 0, stream>>>(xw, inv, rp, col, flist, nf_dev, b1, h1c);

    // layer 2: compact GEMM (nf rows), gather over U rows
    gemm_nn_dyn_kernel<<<(NFCAP + 31) / 32, 256, 0, stream>>>(h1c, W2, xw, nf_dev);
    gather_l2_kernel<<<(U_USERS + 3) / 4, 256, 0, stream>>>(xw, inv, rp, col, remap, b2, out);

    // passthrough rows [U:]
    hipMemcpyAsync(out + (size_t)U_USERS * F_DIM, x + (size_t)U_USERS * F_DIM,
                   (size_t)(n - U_USERS) * F_DIM * sizeof(float),
                   hipMemcpyDeviceToDevice, stream);
}

// Round 7
// 333.990 us; speedup vs baseline: 1.5869x; 1.1856x over previous
//
#include <hip/hip_runtime.h>

// GCNLinkPredictor: 2-layer GCN, N=100000, E=3.2M, F=128, U=1000.
// R7: fp16 xw. (a) GEMM moves to MFMA f16 (no fp32 MFMA on CDNA4; fp16 in,
// fp32 accumulate): X-tile + W^T staged in LDS fp16, row pad +8 halfs (136)
// -> 2-way bank aliasing (free). (b) gather reads fp16 rows: edge traffic
// halves (548 -> 274 MB). Verified fragment layouts (m89/m91/m120):
// A[m=lane&15][k=quad*8+j], B[n=lane&15][k=quad*8+j], C col=lane&15,
// row=quad*4+reg.

#define F_DIM 128
#define U_USERS 1000
#define SCAN_CHUNK 1024
#define NFCAP 48000     // frontier cap (expected ~33K)
#define NCHUNK 3        // node-space chunks for histogram
#define SBIN 40960      // nodes per chunk (3*40960 >= 100000)
#define SW (SBIN / 2)   // packed words per chunk (2 x u16 per word)
#define PSLICE 85      // edge slices per chunk -> 255 blocks
#define XPAD 136        // fp16 LDS row stride (128 + 8)

using f16x8 = __attribute__((ext_vector_type(8))) _Float16;
using f16x2 = __attribute__((ext_vector_type(2))) _Float16;
using f32x4 = __attribute__((ext_vector_type(4))) float;

union H4 { uint2 u2; _Float16 h[4]; };

// ---- histogram: LDS packed counters, no global atomics ----
__global__ __launch_bounds__(1024) void hist_kernel(const int* __restrict__ src,
                                                    const int* __restrict__ dst,
                                                    unsigned int* __restrict__ partial,
                                                    int* __restrict__ fr, int E, int n) {
    __shared__ unsigned int h[SW];   // 80 KB
    int tid = threadIdx.x;
    int c = blockIdx.x % NCHUNK;
    int p = blockIdx.x / NCHUNK;
    for (int i = tid; i < SW; i += 1024) h[i] = 0u;
    __syncthreads();

    int lo = c * SBIN;
    int hi = lo + SBIN;
    int len = (E + PSLICE - 1) / PSLICE;
    int base = p * len;
    int end = min(E, base + len);
    for (int e = base + tid; e < end; e += 1024) {
        int d = dst[e];
        if ((unsigned)d < (unsigned)n) {
            if (d >= lo && d < hi) {
                int local = d - lo;
                atomicAdd(&h[local >> 1], 1u << ((local & 1) << 4));  // LDS atomic
            }
            if (c == 0 && d < U_USERS) {
                int s = src[e];
                if ((unsigned)s < (unsigned)n) fr[s] = 1;
            }
        }
    }
    __syncthreads();
    unsigned int* outp = partial + ((size_t)(c * PSLICE + p)) * SW;
    for (int i = tid; i < SW; i += 1024) outp[i] = h[i];
}

// ---- reduce partials -> deg; fused prep: inv, degF, fr[i<U]=1 ----
__global__ void reduce_prep_kernel(const unsigned int* __restrict__ partial,
                                   float* __restrict__ inv, int* __restrict__ fr,
                                   int* __restrict__ degF, int n) {
    int t = blockIdx.x * blockDim.x + threadIdx.x;
    if (t >= NCHUNK * SW) return;
    int c = t / SW, w = t % SW;
    unsigned int a0 = 0, a1 = 0;
    const unsigned int* basep = partial + (size_t)c * PSLICE * SW + w;
#pragma unroll 5
    for (int p = 0; p < PSLICE; ++p) {
        unsigned int v = basep[(size_t)p * SW];
        a0 += v & 0xFFFFu;
        a1 += v >> 16;
    }
    int i0 = c * SBIN + 2 * w;
#pragma unroll
    for (int k = 0; k < 2; ++k) {
        int i = i0 + k;
        unsigned int dg = k ? a1 : a0;
        if (i < n) {
            inv[i] = rsqrtf((float)dg + 1.0f);
            bool isfr = (i < U_USERS) || (fr[i] != 0);
            if (i < U_USERS) fr[i] = 1;
            degF[i] = isfr ? (int)dg : 0;
        }
    }
}

// ---- dual exclusive scan (degF -> rp, fr -> remap), 3 kernels ----
__global__ void scan_reduce2_kernel(const int* __restrict__ dA, const int* __restrict__ dB,
                                    int* __restrict__ pA, int* __restrict__ pB, int n) {
    __shared__ int sdata[256];
    int b = blockIdx.x, t = threadIdx.x;
    int base = b * SCAN_CHUNK;
    int sumA = 0, sumB = 0;
#pragma unroll
    for (int i = 0; i < 4; ++i) {
        int idx = base + t + 256 * i;
        if (idx < n) { sumA += dA[idx]; sumB += dB[idx]; }
    }
    sdata[t] = sumA; __syncthreads();
    for (int s = 128; s > 0; s >>= 1) { if (t < s) sdata[t] += sdata[t + s]; __syncthreads(); }
    if (t == 0) pA[b] = sdata[0];
    __syncthreads();
    sdata[t] = sumB; __syncthreads();
    for (int s = 128; s > 0; s >>= 1) { if (t < s) sdata[t] += sdata[t + s]; __syncthreads(); }
    if (t == 0) pB[b] = sdata[0];
}

__global__ void scan_partials2_kernel(int* __restrict__ pA, int* __restrict__ pB, int nb) {
    int t = threadIdx.x;
    if (t == 0)  { int run = 0; for (int i = 0; i < nb; ++i) { int v = pA[i]; pA[i] = run; run += v; } }
    if (t == 64) { int run = 0; for (int i = 0; i < nb; ++i) { int v = pB[i]; pB[i] = run; run += v; } }
}

__global__ void scan_final2_kernel(const int* __restrict__ dA, const int* __restrict__ pA,
                                   int* __restrict__ rp,
                                   const int* __restrict__ dB, const int* __restrict__ pB,
                                   int* __restrict__ remap,
                                   int* __restrict__ flist, int* __restrict__ nf_dev, int n) {
    __shared__ int sthread[256];
    int b = blockIdx.x, t = threadIdx.x;
    int base = b * SCAN_CHUNK;
    {
        int v[4]; int sum = 0;
#pragma unroll
        for (int i = 0; i < 4; ++i) { int idx = base + 4 * t + i; v[i] = (idx < n) ? dA[idx] : 0; sum += v[i]; }
        sthread[t] = sum; __syncthreads();
        for (int ofs = 1; ofs < 256; ofs <<= 1) {
            int val = (t >= ofs) ? sthread[t - ofs] : 0;
            __syncthreads(); sthread[t] += val; __syncthreads();
        }
        int run = sthread[t] - sum + pA[b];
#pragma unroll
        for (int i = 0; i < 4; ++i) { int idx = base + 4 * t + i; if (idx < n) rp[idx] = run; run += v[i]; }
        __syncthreads();
    }
    {
        int v[4]; int sum = 0;
#pragma unroll
        for (int i = 0; i < 4; ++i) { int idx = base + 4 * t + i; v[i] = (idx < n) ? dB[idx] : 0; sum += v[i]; }
        sthread[t] = sum; __syncthreads();
        for (int ofs = 1; ofs < 256; ofs <<= 1) {
            int val = (t >= ofs) ? sthread[t - ofs] : 0;
            __syncthreads(); sthread[t] += val; __syncthreads();
        }
        int run = sthread[t] - sum + pB[b];
#pragma unroll
        for (int i = 0; i < 4; ++i) {
            int idx = base + 4 * t + i;
            if (idx < n) {
                remap[idx] = run;
                if (v[i] && run < NFCAP) flist[run] = idx;
                if (idx == n - 1) *nf_dev = min(run + v[i], NFCAP);
            }
            run += v[i];
        }
    }
}

// ---- CSR fill (frontier rows only) ----
__global__ void fill_csr_kernel(const int* __restrict__ src, const int* __restrict__ dst,
                                const int* __restrict__ fr,
                                int* __restrict__ rp, int* __restrict__ col, int E, int n) {
    int e = blockIdx.x * blockDim.x + threadIdx.x;
    if (e < E) {
        int d = dst[e], s = src[e];
        if ((unsigned)d < (unsigned)n && (unsigned)s < (unsigned)n && fr[d]) {
            int pos = atomicAdd(&rp[d], 1);
            if ((unsigned)pos < (unsigned)E) col[pos] = s;
        }
    }
}

// ---- MFMA fp16 GEMM: outh[n,128] = f16(X[n,128] @ W[128,128]) ----
// 256 threads = 4 waves, 64 rows/block. LDS: Xs fp16 [64][136] (17KB) +
// Wt fp16 (W transposed, [n][k]) [128][136] (34KB) -> 3 blocks/CU.
// Wave w: rows [16w,16w+16), all 128 cols (8 col-tiles), K=128 in 4 chunks.
__device__ __forceinline__ void gemm_mfma_body(const float* __restrict__ X,
                                               const float* __restrict__ W,
                                               _Float16* __restrict__ outh,
                                               int nrows, int rowBase) {
    __shared__ _Float16 Wt[128 * XPAD];   // [n][k]
    __shared__ _Float16 Xs[64 * XPAD];    // [r][k]

    int tid = threadIdx.x;

    // stage W transposed: 4096 float4s / 256 threads = 16 each
    const float4* W4 = (const float4*)W;
#pragma unroll
    for (int i = 0; i < 16; ++i) {
        int j = tid + 256 * i;        // j = k*32 + n4
        int k = j >> 5;
        int n4 = j & 31;
        float4 v = W4[j];
#pragma unroll
        for (int q = 0; q < 4; ++q)
            Wt[(n4 * 4 + q) * XPAD + k] = (_Float16)((const float*)&v)[q];
    }

    // stage X tile fp16 row-major: 2048 float4s / 256 = 8 each
#pragma unroll
    for (int i = 0; i < 8; ++i) {
        int j = tid + 256 * i;        // j = r*32 + k4
        int r = j >> 5;
        int k4 = j & 31;
        int row = rowBase + r;
        float4 v = make_float4(0.f, 0.f, 0.f, 0.f);
        if (row < nrows) v = ((const float4*)(X + (size_t)row * F_DIM))[k4];
        H4 p;
#pragma unroll
        for (int q = 0; q < 4; ++q) p.h[q] = (_Float16)((const float*)&v)[q];
        *(uint2*)&Xs[r * XPAD + k4 * 4] = p.u2;
    }
    __syncthreads();

    int w = tid >> 6;
    int lane = tid & 63;
    int m = lane & 15;
    int quad = lane >> 4;
    int R = w * 16;                   // block-local row base for this wave

    f32x4 acc[8];
#pragma unroll
    for (int i = 0; i < 8; ++i) acc[i] = (f32x4){0.f, 0.f, 0.f, 0.f};

#pragma unroll
    for (int kc = 0; kc < 4; ++kc) {
        f16x8 a = *(const f16x8*)&Xs[(R + m) * XPAD + kc * 32 + quad * 8];
#pragma unroll
        for (int ct = 0; ct < 8; ++ct) {
            f16x8 b = *(const f16x8*)&Wt[(ct * 16 + m) * XPAD + kc * 32 + quad * 8];
            acc[ct] = __builtin_amdgcn_mfma_f32_16x16x32_f16(a, b, acc[ct], 0, 0, 0);
        }
    }

#pragma unroll
    for (int ct = 0; ct < 8; ++ct) {
#pragma unroll
        for (int reg = 0; reg < 4; ++reg) {
            int row = rowBase + R + quad * 4 + reg;
            if (row < nrows)
                outh[(size_t)row * F_DIM + ct * 16 + m] = (_Float16)acc[ct][reg];
        }
    }
}

__global__ __launch_bounds__(256) void gemm_f16_kernel(const float* __restrict__ X,
                                                       const float* __restrict__ W,
                                                       _Float16* __restrict__ outh, int nrows) {
    gemm_mfma_body(X, W, outh, nrows, blockIdx.x * 64);
}

__global__ __launch_bounds__(256) void gemm_f16_dyn_kernel(const float* __restrict__ X,
                                                           const float* __restrict__ W,
                                                           _Float16* __restrict__ outh,
                                                           const int* __restrict__ nrows_p) {
    int nrows = *nrows_p;
    int rowBase = blockIdx.x * 64;
    if (rowBase >= nrows) return;
    gemm_mfma_body(X, W, outh, nrows, rowBase);
}

// ---- layer-1 gather over compact frontier rows (fp16 rows, fp32 accum) ----
__global__ __launch_bounds__(256) void gather_l1_kernel(const _Float16* __restrict__ xwh,
                                                        const float* __restrict__ inv,
                                                        const int* __restrict__ rp,
                                                        const int* __restrict__ col,
                                                        const int* __restrict__ flist,
                                                        const int* __restrict__ nf_p,
                                                        const float* __restrict__ b,
                                                        float* __restrict__ h1c) {
    int ci = blockIdx.x * 4 + (threadIdx.x >> 6);
    if (ci >= *nf_p) return;
    int lane = threadIdx.x & 63;
    int node = flist[ci];
    int start = (node == 0) ? 0 : rp[node - 1];
    int end = rp[node];

    float accx = 0.f, accy = 0.f;
    for (int base = start; base < end; base += 64) {
        int j = base + lane;
        int s_l = 0; float c_l = 0.f;
        if (j < end) { s_l = col[j]; c_l = inv[s_l]; }
        int cnt = min(64, end - base);
        int i = 0;
        for (; i + 4 <= cnt; i += 4) {
            int s0 = __shfl(s_l, i + 0); float f0 = __shfl(c_l, i + 0);
            int s1 = __shfl(s_l, i + 1); float f1 = __shfl(c_l, i + 1);
            int s2 = __shfl(s_l, i + 2); float f2 = __shfl(c_l, i + 2);
            int s3 = __shfl(s_l, i + 3); float f3 = __shfl(c_l, i + 3);
            f16x2 v0 = ((const f16x2*)(xwh + (size_t)s0 * F_DIM))[lane];
            f16x2 v1 = ((const f16x2*)(xwh + (size_t)s1 * F_DIM))[lane];
            f16x2 v2 = ((const f16x2*)(xwh + (size_t)s2 * F_DIM))[lane];
            f16x2 v3 = ((const f16x2*)(xwh + (size_t)s3 * F_DIM))[lane];
            accx += (float)v0[0] * f0 + (float)v1[0] * f1 + (float)v2[0] * f2 + (float)v3[0] * f3;
            accy += (float)v0[1] * f0 + (float)v1[1] * f1 + (float)v2[1] * f2 + (float)v3[1] * f3;
        }
        for (; i < cnt; ++i) {
            int s0 = __shfl(s_l, i); float f0 = __shfl(c_l, i);
            f16x2 v0 = ((const f16x2*)(xwh + (size_t)s0 * F_DIM))[lane];
            accx += (float)v0[0] * f0;
            accy += (float)v0[1] * f0;
        }
    }

    float ivd = inv[node];
    f16x2 self = ((const f16x2*)(xwh + (size_t)node * F_DIM))[lane];
    float vx = accx * ivd + (float)self[0] * ivd * ivd + b[lane * 2];
    float vy = accy * ivd + (float)self[1] * ivd * ivd + b[lane * 2 + 1];
    vx = vx > 0.f ? vx : expf(vx) - 1.f;
    vy = vy > 0.f ? vy : expf(vy) - 1.f;
    ((float2*)(h1c + (size_t)ci * F_DIM))[lane] = make_float2(vx, vy);
}

// ---- layer-2 gather over rows [0,U) (fp16 compact rows) ----
__global__ __launch_bounds__(256) void gather_l2_kernel(const _Float16* __restrict__ xwc,
                                                        const float* __restrict__ inv,
                                                        const int* __restrict__ rp,
                                                        const int* __restrict__ col,
                                                        const int* __restrict__ remap,
                                                        const float* __restrict__ b,
                                                        float* __restrict__ out) {
    int node = blockIdx.x * 4 + (threadIdx.x >> 6);
    if (node >= U_USERS) return;
    int lane = threadIdx.x & 63;
    int start = (node == 0) ? 0 : rp[node - 1];
    int end = rp[node];

    float accx = 0.f, accy = 0.f;
    for (int base = start; base < end; base += 64) {
        int j = base + lane;
        int r_l = 0; float c_l = 0.f;
        if (j < end) { int s = col[j]; c_l = inv[s]; r_l = remap[s]; }
        int cnt = min(64, end - base);
        for (int i = 0; i < cnt; ++i) {
            int rr = __shfl(r_l, i); float f0 = __shfl(c_l, i);
            f16x2 v0 = ((const f16x2*)(xwc + (size_t)rr * F_DIM))[lane];
            accx += (float)v0[0] * f0;
            accy += (float)v0[1] * f0;
        }
    }

    float ivd = inv[node];
    f16x2 self = ((const f16x2*)(xwc + (size_t)node * F_DIM))[lane];  // remap[node]==node for node<U
    float vx = accx * ivd + (float)self[0] * ivd * ivd + b[lane * 2];
    float vy = accy * ivd + (float)self[1] * ivd * ivd + b[lane * 2 + 1];
    vx = vx > 0.f ? vx : expf(vx) - 1.f;
    vy = vy > 0.f ? vy : expf(vy) - 1.f;
    ((float2*)(out + (size_t)node * F_DIM))[lane] = make_float2(vx, vy);
}

extern "C" void kernel_launch(void* const* d_in, const int* in_sizes, int n_in,
                              void* d_out, int out_size, void* d_ws, size_t ws_size,
                              hipStream_t stream) {
    const float* x  = (const float*)d_in[0];
    const int*   ei = (const int*)d_in[1];   // [2, E] int32
    const float* W1 = (const float*)d_in[2];
    const float* b1 = (const float*)d_in[3];
    const float* W2 = (const float*)d_in[4];
    const float* b2 = (const float*)d_in[5];
    float* out = (float*)d_out;

    int n = in_sizes[0] / F_DIM;   // 100000
    int E = in_sizes[1] / 2;       // 3200000
    const int* srcI = ei;
    const int* dstI = ei + E;

    // workspace layout (~110 MB)
    _Float16* xwh = (_Float16*)d_ws;                 // n*128 halfs (xw1 / xwc, 25.6MB)
    float* h1c   = (float*)(xwh + (size_t)n * F_DIM);// NFCAP*128 f (24.6MB)
    float* inv   = h1c + (size_t)NFCAP * F_DIM;      // n f
    int* fr      = (int*)(inv + n);                  // n
    int* degF    = fr + n;                           // n
    int* remap   = degF + n;                         // n
    int* rp      = remap + n;                        // n
    int* flist   = rp + n;                           // NFCAP
    int* pA      = flist + NFCAP;                    // 1024
    int* pB      = pA + 1024;                        // 1024
    int* nf_dev  = pB + 1024;                        // 1 (+pad)
    int* col     = nf_dev + 16;                      // E
    unsigned int* partialH = (unsigned int*)(col + E);  // NCHUNK*PSLICE*SW

    int nb = (n + SCAN_CHUNK - 1) / SCAN_CHUNK;      // 98

    hipMemsetAsync(fr, 0, (size_t)n * sizeof(int), stream);

    hist_kernel<<<NCHUNK * PSLICE, 1024, 0, stream>>>(srcI, dstI, partialH, fr, E, n);
    reduce_prep_kernel<<<(NCHUNK * SW + 255) / 256, 256, 0, stream>>>(partialH, inv, fr, degF, n);

    scan_reduce2_kernel<<<nb, 256, 0, stream>>>(degF, fr, pA, pB, n);
    scan_partials2_kernel<<<1, 128, 0, stream>>>(pA, pB, nb);
    scan_final2_kernel<<<nb, 256, 0, stream>>>(degF, pA, rp, fr, pB, remap, flist, nf_dev, n);

    fill_csr_kernel<<<(E + 255) / 256, 256, 0, stream>>>(srcI, dstI, fr, rp, col, E, n);

    // layer 1: full MFMA GEMM (fp16 out), frontier-only gather
    gemm_f16_kernel<<<(n + 63) / 64, 256, 0, stream>>>(x, W1, xwh, n);
    gather_l1_kernel<<<(NFCAP + 3) / 4, 256, 0, stream>>>(xwh, inv, rp, col, flist, nf_dev, b1, h1c);

    // layer 2: compact MFMA GEMM (nf rows), gather over U rows
    gemm_f16_dyn_kernel<<<(NFCAP + 63) / 64, 256, 0, stream>>>(h1c, W2, xwh, nf_dev);
    gather_l2_kernel<<<(U_USERS + 3) / 4, 256, 0, stream>>>(xwh, inv, rp, col, remap, b2, out);

    // passthrough rows [U:]
    hipMemcpyAsync(out + (size_t)U_USERS * F_DIM, x + (size_t)U_USERS * F_DIM,
                   (size_t)(n - U_USERS) * F_DIM * sizeof(float),
                   hipMemcpyDeviceToDevice, stream);
}